// Round 4
// baseline (229.710 us; speedup 1.0000x reference)
//
#include <hip/hip_runtime.h>

#define B_ 256
#define T_ 2048
#define F_ 20
#define NT (B_*T_)
#define CH 16
#define NCH (T_/CH)   // 128 chunks

typedef __bf16 bf16x8 __attribute__((ext_vector_type(8)));
typedef float  f32x4  __attribute__((ext_vector_type(4)));

__device__ __forceinline__ float ex2(float x){ return __builtin_amdgcn_exp2f(x); }
__device__ __forceinline__ float rcpf_(float x){ return __builtin_amdgcn_rcpf(x); }

// 20*log2(e), 2*log2(e), log2(e), 1/(20*log2(e)) = ln2/20
#define K10F 28.853900817779268f
#define INVK 0.034657359027997264f
#define K1F   2.8853900817779268f
#define LOG2E 1.4426950408889634f

__device__ __forceinline__ float hside(float x){ return 1.0f - rcpf_(ex2(K10F*x) + 1.0f); }
__device__ __forceinline__ float tanh_f(float z){ return 1.0f - 2.0f*rcpf_(ex2(K1F*z) + 1.0f); }
__device__ __forceinline__ float sigmoid_f(float z){ return rcpf_(1.0f + ex2(-LOG2E*z)); }

// ws float layout:
// pp2   [0, 2NT)     float2 {pet, p}, t-major r = t*256 + b
// wuT   [2NT, 3NT)
// wdT   [3NT, 4NT)
// params[4NT, 12NT)  8 per row r

__global__ __launch_bounds__(256) void prep_kernel(const float* __restrict__ in,
                                                   float* __restrict__ ws){
  int r = blockIdx.x*256 + threadIdx.x;
  if (r >= NT) return;
  int b = r & (B_-1);
  int t = r >> 8;
  const float* src = in + ((size_t)b*T_ + t)*F_;
  ((float2*)ws)[r] = make_float2(src[0], src[2]);  // pet, p
}

// blocks 0..7: pipelined scan (32 batches each; waves: 0=wu,1=rp/hrp,2=wl,3=wd,4=loader,5=writer)
// blocks 8..4103: MFMA MLP (128 rows each)
__global__ __launch_bounds__(512) void fused_kernel(const float* __restrict__ in,
    const float* __restrict__ w1, const float* __restrict__ b1,
    const float* __restrict__ w2, const float* __restrict__ b2,
    const float* __restrict__ w3, const float* __restrict__ b3,
    float* __restrict__ ws){
  extern __shared__ char sm[];
  float* params = ws + 4*(size_t)NT;

  if (blockIdx.x < 8) {
    // ================== scaled-space pipelined scan ==================
    const float2* pp2 = (const float2*)ws;
    float* wuT = ws + 2*(size_t)NT;
    float* wdT = ws + 3*(size_t)NT;
    float2* ppL = (float2*)sm;              // [2][CH][32] {PET', PP'}   8 KB
    float2* dkb = (float2*)(sm + 8192);     // [2][CH][32] {dK, BASE'}   8 KB
    float2* rhb = (float2*)(sm + 16384);    // [2][CH][32] {RP', HRP}    8 KB
    float2* qbb = (float2*)(sm + 24576);    // [2][CH][32] {QV', B2'}    8 KB
    float*  bb2 = (float*)(sm + 32768);     // [2][CH][32] BASE relay    4 KB
    float*  wub = (float*)(sm + 36864);     // [2][CH][32] Wu'           4 KB
    float*  wdb = (float*)(sm + 40960);     // [2][CH][32] WD'           4 KB

    int tid  = threadIdx.x;
    int wv   = tid >> 6;
    int l64  = tid & 63;
    bool act = l64 < 32;
    int lane = l64 & 31;
    int boff = blockIdx.x * 32;

    float Wu = 0.0f, WL = 0.0f, WD = 0.0f;   // state in K-scaled space

    if (wv == 4 && act){                      // preload chunk 0
      float2 v[CH];
      #pragma unroll
      for (int s = 0; s < CH; ++s) v[s] = pp2[s*B_ + boff + lane];
      #pragma unroll
      for (int s = 0; s < CH; ++s)
        ppL[s*32 + lane] = make_float2(K10F*v[s].x, K10F*(v[s].y - v[s].x));
    }
    __syncthreads();

    for (int it = 0; it < NCH + 4; ++it){
      if (wv == 0){                           // wu recurrence
        int c = it;
        if (c < NCH && act){
          int par = c & 1;
          #pragma unroll
          for (int s = 0; s < CH; ++s){
            float2 pe = ppL[(par*CH + s)*32 + lane];
            float t1  = Wu - pe.x;
            float r   = rcpf_(ex2(t1) + 1.0f);
            float WuPP= Wu + pe.y;            // off-chain
            float Wn  = fmaf(-t1, r, WuPP);
            float dK  = -t1*r;                // = K*d1
            float BASE= pe.y + dK;            // = K*base
            dkb[(par*CH + s)*32 + lane] = make_float2(dK, BASE);
            wub[(par*CH + s)*32 + lane] = Wn;
            Wu = Wn;
          }
        }
      } else if (wv == 1){                    // stateless RP', HRP
        int c = it - 1;
        if (c >= 0 && c < NCH && act){
          int par = c & 1;
          #pragma unroll
          for (int s = 0; s < CH; ++s){
            float2 db = dkb[(par*CH + s)*32 + lane];
            float r1  = rcpf_(ex2(db.x) + 1.0f);
            float RP  = fmaf(-db.x, r1, db.x);          // = K*rp
            float HRP = 1.0f - rcpf_(ex2(RP) + 1.0f);   // = h(rp)
            rhb[(par*CH + s)*32 + lane] = make_float2(RP, HRP);
            bb2[(par*CH + s)*32 + lane] = db.y;
          }
        }
      } else if (wv == 2){                    // wl recurrence
        int c = it - 2;
        if (c >= 0 && c < NCH && act){
          int par = c & 1;
          #pragma unroll
          for (int s = 0; s < CH; ++s){
            float2 rh  = rhb[(par*CH + s)*32 + lane];
            float BASE = bb2[(par*CH + s)*32 + lane];
            float D2   = rh.x - WL;
            float r    = rcpf_(ex2(D2) + 1.0f);
            float et22 = fmaf(D2, r, WL);
            float WLB  = WL + BASE;           // off-chain
            float Wn   = fmaf(-rh.y, et22, WLB);
            float ET2  = rh.y * et22;         // off-chain
            qbb[(par*CH + s)*32 + lane] = make_float2(rh.x - ET2, BASE - ET2);
            WL = Wn;
          }
        }
      } else if (wv == 3){                    // wd recurrence
        int c = it - 3;
        if (c >= 0 && c < NCH && act){
          int par = c & 1;
          #pragma unroll
          for (int s = 0; s < CH; ++s){
            float2 qb  = qbb[(par*CH + s)*32 + lane];
            float hqv  = 1.0f - rcpf_(ex2(qb.x) + 1.0f);
            float D3   = qb.x - WD;
            float r    = rcpf_(ex2(D3) + 1.0f);
            float et33 = fmaf(D3, r, WD);
            float WDB  = WD + qb.y;           // off-chain
            float Wn   = fmaf(-hqv, et33, WDB);
            wdb[(par*CH + s)*32 + lane] = Wn;
            WD = Wn;
          }
        }
      } else if (wv == 4){                    // loader: chunk it+1
        int cn = it + 1;
        if (cn < NCH && act){
          float2 v[CH];
          #pragma unroll
          for (int s = 0; s < CH; ++s) v[s] = pp2[(cn*CH + s)*B_ + boff + lane];
          int par = cn & 1;
          #pragma unroll
          for (int s = 0; s < CH; ++s)
            ppL[(par*CH + s)*32 + lane] = make_float2(K10F*v[s].x, K10F*(v[s].y - v[s].x));
        }
      } else if (wv == 5){                    // writer: wu chunk it-1, wd chunk it-4
        int cw = it - 1;
        if (cw >= 0 && cw < NCH && act){
          int par = cw & 1;
          #pragma unroll
          for (int s = 0; s < CH; ++s)
            wuT[(cw*CH + s)*B_ + boff + lane] = wub[(par*CH + s)*32 + lane] * INVK;
        }
        int cd = it - 4;
        if (cd >= 0 && cd < NCH && act){
          int par = cd & 1;
          #pragma unroll
          for (int s = 0; s < CH; ++s)
            wdT[(cd*CH + s)*B_ + boff + lane] = wdb[(par*CH + s)*32 + lane] * INVK;
        }
      }
      __syncthreads();
    }
    return;
  }

  // ================== MFMA MLP path ==================
  __bf16* w1f  = (__bf16*)sm;                // 8192 B
  __bf16* w2f  = (__bf16*)(sm + 8192);       // 32768 B
  float*  b1s  = (float*)(sm + 40960);
  float*  b2s  = (float*)(sm + 41984);
  float*  w3s  = (float*)(sm + 42240);
  float*  b3s  = (float*)(sm + 44288);
  __bf16* hbufA= (__bf16*)(sm + 44320);      // 8 waves × 16×72 bf16

  int tid = threadIdx.x;

  for (int s = tid; s < 16*32*8; s += 512) w1f[s] = (__bf16)0.0f;
  __syncthreads();
  for (int idx = tid; idx < 15*256; idx += 512){   // w1: (k,n) k<15
    int k = idx >> 8, n = idx & 255;
    int ct = n >> 4;
    int l  = ((k>>3)*16) + (n & 15);
    int j  = k & 7;
    w1f[(ct*32 + l)*8 + j] = (__bf16)w1[idx];
  }
  for (int idx = tid; idx < 256*64; idx += 512){   // w2: (k,n)
    int k = idx >> 6, n = idx & 63;
    int kb = k >> 5;
    int lq = (k >> 3) & 3;
    int j  = k & 7;
    int ct = n >> 4;
    int l  = lq*16 + (n & 15);
    w2f[((kb*4 + ct)*64 + l)*8 + j] = (__bf16)w2[idx];
  }
  if (tid < 256) b1s[tid] = b1[tid];
  if (tid < 64)  b2s[tid] = b2[tid];
  if (tid < 512) w3s[tid] = w3[tid];
  if (tid < 8)   b3s[tid] = b3[tid];
  __syncthreads();

  int lane = tid & 63;
  int wv   = tid >> 6;
  int m    = lane & 15;
  int q    = lane >> 4;
  int r0   = (blockIdx.x - 8)*128 + wv*16;

  int rowA = r0 + m;
  int bA = rowA & (B_-1), tA = rowA >> 8;
  const float* ap = in + ((size_t)bA*T_ + tA)*F_ + 5;
  bf16x8 a1;
  #pragma unroll
  for (int j = 0; j < 8; ++j){
    int k = q*8 + j;
    float v = (k < 15) ? ap[k] : 0.0f;
    a1[j] = (__bf16)v;
  }

  __bf16* hb = hbufA + wv*1152;
  f32x4 zero4 = {0.0f, 0.0f, 0.0f, 0.0f};
  bf16x8 zero8;
  #pragma unroll
  for (int j = 0; j < 8; ++j) zero8[j] = (__bf16)0.0f;

  f32x4 acc2[4] = {zero4, zero4, zero4, zero4};

  #pragma unroll
  for (int p = 0; p < 4; ++p){
    #pragma unroll
    for (int c4 = 0; c4 < 4; ++c4){
      int ct = p*4 + c4;
      bf16x8 bw = zero8;
      if (lane < 32) bw = *(const bf16x8*)&w1f[(ct*32 + lane)*8];
      f32x4 c1 = __builtin_amdgcn_mfma_f32_16x16x32_bf16(a1, bw, zero4, 0, 0, 0);
      int f = c4*16 + m;
      float bb = b1s[p*64 + f];
      #pragma unroll
      for (int i = 0; i < 4; ++i){
        float h = tanh_f(c1[i] + bb);
        hb[(q*4 + i)*72 + f] = (__bf16)h;
      }
    }
    #pragma unroll
    for (int kb = 0; kb < 2; ++kb){
      bf16x8 a2 = *(const bf16x8*)&hb[m*72 + q*8 + kb*32];
      #pragma unroll
      for (int ct = 0; ct < 4; ++ct){
        bf16x8 bw2 = *(const bf16x8*)&w2f[(((p*2 + kb)*4 + ct)*64 + lane)*8];
        acc2[ct] = __builtin_amdgcn_mfma_f32_16x16x32_bf16(a2, bw2, acc2[ct], 0, 0, 0);
      }
    }
  }

  #pragma unroll
  for (int ct = 0; ct < 4; ++ct){
    int f = ct*16 + m;
    float bb = b2s[f];
    #pragma unroll
    for (int i = 0; i < 4; ++i){
      float h = tanh_f(acc2[ct][i] + bb);
      hb[(q*4 + i)*72 + f] = (__bf16)h;
    }
  }

  float z0 = b3s[2*q], z1 = b3s[2*q + 1];
  #pragma unroll
  for (int kb3 = 0; kb3 < 8; ++kb3){
    bf16x8 hv8 = *(const bf16x8*)&hb[m*72 + kb3*8];
    #pragma unroll
    for (int j = 0; j < 8; ++j){
      float hv = (float)hv8[j];
      int k = kb3*8 + j;
      z0 = fmaf(hv, w3s[k*8 + 2*q],     z0);
      z1 = fmaf(hv, w3s[k*8 + 2*q + 1], z1);
    }
  }
  int rowO = r0 + m;
  float2 outp = make_float2(sigmoid_f(z0), sigmoid_f(z1));
  *(float2*)&params[(size_t)rowO*8 + 2*q] = outp;
}

// 64t × 64b tile; coalesced reads, LDS transpose, coalesced 256B out-writes
__global__ __launch_bounds__(256) void final_kernel(const float* __restrict__ ws,
                                                    float* __restrict__ out){
  __shared__ float tile[64*65];
  int tb = blockIdx.x & 31;
  int bb = blockIdx.x >> 5;
  int t0 = tb*64, b0 = bb*64;
  int tid = threadIdx.x;
  const float2* pp2 = (const float2*)ws;
  const float* wuT  = ws + 2*(size_t)NT;
  const float* wdT  = ws + 3*(size_t)NT;
  const float* params = ws + 4*(size_t)NT;

  #pragma unroll
  for (int k = 0; k < 16; ++k){
    int idx = k*256 + tid;
    int tl = idx >> 6, bl = idx & 63;
    int r = (t0 + tl)*B_ + b0 + bl;
    float p  = pp2[r].y;
    float wu = wuT[r], wd = wdT[r];
    const float4* pp = (const float4*)(params + (size_t)r*8);
    float4 p0 = pp[0], p1 = pp[1];
    // reference calls _runoff(wu, wd, wl, p, wum, wdm, wlm, b, c):
    //   state wd lands in "wl" slot; param wdm in "wlm" slot; param wlm in "wdm" slot
    float wum   = fmaf(p0.x, 19.9f, 0.1f);
    float wlm_s = fmaf(p0.z, 30.0f, 60.0f);
    float wdm_s = fmaf(p0.y, 60.0f, 60.0f);
    float cc = fmaf(p1.x, 0.19f, 0.01f);
    float bcoef = fmaf(p0.w, 0.30f, 0.10f);
    float wt = wum + wlm_s + wdm_s;
    float xu = wu / wt;
    float xd = wd / wt;
    float s  = cc*xu*xu + bcoef*xd*xd;
    float ps = p - s;
    float runoff = hside(ps)*ps;
    float k1p = fmaf(p1.y, 0.69f, 0.01f);
    float k2p = fmaf(p1.z, 0.69f, 0.01f);
    float k3p = fmaf(p1.w, 0.89f, 0.01f);
    float sr  = k1p*runoff;
    float itf = k2p*(runoff - sr);
    float bf  = k3p*(runoff - sr - itf);
    tile[bl*65 + tl] = sr + 0.5f*itf + 0.25f*bf;
  }
  __syncthreads();
  #pragma unroll
  for (int k = 0; k < 16; ++k){
    int idx = k*256 + tid;
    int tl2 = idx & 63, bl2 = idx >> 6;
    out[(size_t)(b0 + bl2)*T_ + t0 + tl2] = tile[bl2*65 + tl2];
  }
}

extern "C" void kernel_launch(void* const* d_in, const int* in_sizes, int n_in,
                              void* d_out, int out_size, void* d_ws, size_t ws_size,
                              hipStream_t stream) {
  const float* in = (const float*)d_in[0];
  const float* w1 = (const float*)d_in[1];
  const float* b1 = (const float*)d_in[2];
  const float* w2 = (const float*)d_in[3];
  const float* b2 = (const float*)d_in[4];
  const float* w3 = (const float*)d_in[5];
  const float* b3 = (const float*)d_in[6];
  float* out = (float*)d_out;
  float* ws  = (float*)d_ws;

  prep_kernel <<<NT/256,      256, 0,     stream>>>(in, ws);
  fused_kernel<<<NT/128 + 8,  512, 62752, stream>>>(in, w1, b1, w2, b2, w3, b3, ws);
  final_kernel<<<128,         256, 0,     stream>>>(ws, out);
}